// Round 6
// baseline (507.518 us; speedup 1.0000x reference)
//
#include <hip/hip_runtime.h>
#include <hip/hip_bf16.h>
#include <hip/hip_fp16.h>

typedef _Float16 f16;
typedef _Float16 f16x8 __attribute__((ext_vector_type(8)));
typedef _Float16 f16x4 __attribute__((ext_vector_type(4)));
typedef float f32x4 __attribute__((ext_vector_type(4)));

#define NP   4096   // H*W
#define NB   8      // batch
#define CINC 256    // input channels
#define EMB  128
#define OUTC 256
#define BN_EPS 1e-5f

#define DSZ  ((size_t)NB * NP * EMB)      // 4194304 halves, per-dir tensor
#define TSZ  (2 * DSZ)                    // 8388608 halves

// =======================================================================
// prep_x: X fp32 [b][256][4096] -> XT f16 [b][n][256]   (one stream)
// =======================================================================
__global__ __launch_bounds__(256) void prep_x_kernel(
    const float* __restrict__ X, f16* __restrict__ XT)
{
    const int n0 = blockIdx.x * 64, c0 = blockIdx.y * 64, b = blockIdx.z;
    const int tid = threadIdx.x;
    __shared__ __align__(16) f16 Xl[64][72];
    const int nl = tid & 63, cq = tid >> 6;   // cq 0..3
    #pragma unroll
    for (int cc = 0; cc < 16; ++cc) {
        const int c = c0 + cc * 4 + cq;
        Xl[nl][cc * 4 + cq] = (f16)X[((size_t)b * CINC + c) * NP + n0 + nl];
    }
    __syncthreads();
    #pragma unroll
    for (int i = 0; i < 2; ++i) {
        const int s2 = i * 256 + tid;
        const int n = s2 >> 3, cg = s2 & 7;
        *(f16x8*)&XT[((size_t)b * NP + n0 + n) * CINC + c0 + cg * 8] =
            *(const f16x8*)&Xl[n][cg * 8];
    }
}

// =======================================================================
// prep_w: convert 6 proj weights + w_proj + 6 biases fp32 -> f16
// Wf layout: p*32768 (p=0..5: q_rgb,k_rgb,v_rgb,q_pl,k_pl,v_pl), wproj at 196608
// =======================================================================
__global__ __launch_bounds__(256) void prep_w_kernel(
    const float* __restrict__ w0, const float* __restrict__ w1,
    const float* __restrict__ w2, const float* __restrict__ w3,
    const float* __restrict__ w4, const float* __restrict__ w5,
    const float* __restrict__ wp,
    const float* __restrict__ b0, const float* __restrict__ b1,
    const float* __restrict__ b2, const float* __restrict__ b3,
    const float* __restrict__ b4, const float* __restrict__ b5,
    f16* __restrict__ Wf, f16* __restrict__ Bf)
{
    const int idx = blockIdx.x * 256 + threadIdx.x;
    if (idx < 196608) {
        const int p = idx >> 15, off = idx & 32767;
        const float* w = p == 0 ? w0 : p == 1 ? w1 : p == 2 ? w2
                       : p == 3 ? w3 : p == 4 ? w4 : w5;
        Wf[idx] = (f16)w[off];
    } else if (idx < 262144) {
        Wf[idx] = (f16)wp[idx - 196608];
    } else if (idx < 262912) {
        const int r = idx - 262144, p = r >> 7, off = r & 127;
        const float* bb = p == 0 ? b0 : p == 1 ? b1 : p == 2 ? b2
                        : p == 3 ? b3 : p == 4 ? b4 : b5;
        Bf[r] = (f16)bb[off];
    }
}

// =======================================================================
// proj6: pure-f16 GEMM, 3 projections of one stream per launch (y = j).
//   p = pbase + j ; s = p>=3 (stream) ; j==0 -> Q[s], j==1 -> K[1-s], j==2 -> V[1-s]
// =======================================================================
__global__ __launch_bounds__(256) void proj6_kernel(
    const f16* __restrict__ XT, const f16* __restrict__ Wf,
    const f16* __restrict__ Bf, const int pbase,
    f16* __restrict__ Qt, f16* __restrict__ Kt, f16* __restrict__ Vn)
{
    const int m0 = blockIdx.x * 128;
    const int p  = pbase + blockIdx.y;
    const int b  = blockIdx.z;
    const int s  = (p >= 3) ? 1 : 0;
    const int j  = p - s * 3;
    const int tid = threadIdx.x;
    const int w = tid >> 6, lane = tid & 63, quad = lane >> 4, lr = lane & 15;

    const f16* W = Wf + (size_t)p * 32768;

    __shared__ __align__(16) f16 smem[128 * 72 * 2];
    f16* Al = smem;             // [128 n][72]
    f16* Bl = smem + 128 * 72;  // [128 d][72]

    f32x4 acc[2][8];
    #pragma unroll
    for (int mi = 0; mi < 2; ++mi)
        #pragma unroll
        for (int ni = 0; ni < 8; ++ni) acc[mi][ni] = (f32x4){0.f, 0.f, 0.f, 0.f};

    for (int kt = 0; kt < 4; ++kt) {
        const int kc0 = kt * 64;
        __syncthreads();
        #pragma unroll
        for (int i = 0; i < 4; ++i) {   // A: straight b128 copy
            const int s2 = i * 256 + tid;
            const int n = s2 >> 3, cg = s2 & 7;
            *(f16x8*)&Al[n * 72 + cg * 8] =
                *(const f16x8*)&XT[((size_t)b * NP + m0 + n) * CINC + kc0 + cg * 8];
        }
        #pragma unroll
        for (int i = 0; i < 4; ++i) {   // B: straight b128 copy
            const int s2 = i * 256 + tid;
            const int d = s2 >> 3, cg = s2 & 7;
            *(f16x8*)&Bl[d * 72 + cg * 8] =
                *(const f16x8*)&W[(size_t)d * CINC + kc0 + cg * 8];
        }
        __syncthreads();
        #pragma unroll
        for (int ks = 0; ks < 2; ++ks) {
            f16x8 af[2], bfr[8];
            #pragma unroll
            for (int mi = 0; mi < 2; ++mi)
                af[mi] = *(const f16x8*)&Al[(w * 32 + mi * 16 + lr) * 72 + ks * 32 + quad * 8];
            #pragma unroll
            for (int ni = 0; ni < 8; ++ni)
                bfr[ni] = *(const f16x8*)&Bl[(ni * 16 + lr) * 72 + ks * 32 + quad * 8];
            #pragma unroll
            for (int mi = 0; mi < 2; ++mi)
                #pragma unroll
                for (int ni = 0; ni < 8; ++ni)
                    acc[mi][ni] = __builtin_amdgcn_mfma_f32_16x16x32_f16(
                        af[mi], bfr[ni], acc[mi][ni], 0, 0, 0);
        }
    }

    float bias[8];
    #pragma unroll
    for (int ni = 0; ni < 8; ++ni) bias[ni] = (float)Bf[p * 128 + ni * 16 + lr];

    if (j < 2) {
        f16* out = (j == 0) ? (Qt + (size_t)s * DSZ) : (Kt + (size_t)(1 - s) * DSZ);
        #pragma unroll
        for (int mi = 0; mi < 2; ++mi)
            #pragma unroll
            for (int ni = 0; ni < 8; ++ni)
                #pragma unroll
                for (int r = 0; r < 4; ++r) {
                    const int n = m0 + w * 32 + mi * 16 + quad * 4 + r;
                    out[((size_t)b * NP + n) * EMB + ni * 16 + lr] =
                        (f16)(acc[mi][ni][r] + bias[ni]);
                }
    } else {
        f16* outV = Vn + (size_t)(1 - s) * DSZ;
        __syncthreads();
        f16* T = smem;                        // [128 d][136]
        #pragma unroll
        for (int mi = 0; mi < 2; ++mi)
            #pragma unroll
            for (int ni = 0; ni < 8; ++ni)
                #pragma unroll
                for (int r = 0; r < 4; ++r)
                    T[(ni * 16 + lr) * 136 + w * 32 + mi * 16 + quad * 4 + r] =
                        (f16)(acc[mi][ni][r] + bias[ni]);
        __syncthreads();
        for (int s2 = tid; s2 < 2048; s2 += 256) {
            const int d = s2 >> 4, n8 = (s2 & 15) * 8;
            *(f16x8*)&outV[((size_t)b * EMB + d) * NP + m0 + n8] =
                *(const f16x8*)&T[d * 136 + n8];
        }
    }
}

// =======================================================================
// attn: 4 waves/block, 32 q/wave. K-frags direct-global, software-pipelined
// one ms-group ahead (no Kl). V through LDS. XCD swizzle: blocks of one
// (dir,b) share bid%8. S^T via x32 (A=K,B=Q); P lands in x16 A-layout.
// =======================================================================
__global__ __launch_bounds__(256, 2) void attn_kernel(
    const f16* __restrict__ Qt, const f16* __restrict__ Kt,
    const f16* __restrict__ Vn, f16* __restrict__ combT)
{
    const int bid = blockIdx.x;
    const int g = bid & 15, dir = g >> 3, b = g & 7;
    const int n0 = (bid >> 4) * 128;
    const int tid = threadIdx.x;
    const int w = tid >> 6, lane = tid & 63, quad = lane >> 4, lr = lane & 15;

    const f16* Q = Qt + ((size_t)dir * NB + b) * NP * EMB;
    const f16* K = Kt + ((size_t)dir * NB + b) * NP * EMB;
    const f16* V = Vn + ((size_t)dir * NB + b) * (size_t)EMB * NP;

    __shared__ __align__(16) f16 Vl[128][72];   // 18432 B

    const int qbase = n0 + w * 32;

    // Q B-frags: col n = lr, k = cc*32 + quad*8 + j. scale*log2(e) folded.
    f16x8 qf[2][4];
    #pragma unroll
    for (int nt = 0; nt < 2; ++nt)
        #pragma unroll
        for (int cc = 0; cc < 4; ++cc) {
            f16x8 q = *(const f16x8*)&Q[(size_t)(qbase + nt * 16 + lr) * EMB + cc * 32 + quad * 8];
            #pragma unroll
            for (int k = 0; k < 8; ++k)
                q[k] = q[k] * (f16)0.12752749f;   // 128^-0.5 * log2(e)
            qf[nt][cc] = q;
        }

    f32x4 O[2][8];
    #pragma unroll
    for (int nt = 0; nt < 2; ++nt)
        #pragma unroll
        for (int dt = 0; dt < 8; ++dt) O[nt][dt] = (f32x4){0.f, 0.f, 0.f, 0.f};
    float rs[2] = {0.f, 0.f};

    // prefetch K A-frags for (m0=0, ms=0): row = key, k = cc*32+quad*8+j
    f16x8 kfp[4];
    #pragma unroll
    for (int cc = 0; cc < 4; ++cc)
        kfp[cc] = *(const f16x8*)&K[(size_t)lr * EMB + cc * 32 + quad * 8];

    for (int m0 = 0; m0 < NP; m0 += 64) {
        __syncthreads();
        #pragma unroll
        for (int i = 0; i < 4; ++i) {            // V tile: 128 d x 64 m
            const int s2 = i * 256 + tid;
            const int d = s2 >> 3, mc = s2 & 7;
            *(f16x8*)&Vl[d][mc * 8] = *(const f16x8*)&V[(size_t)d * NP + m0 + mc * 8];
        }
        __syncthreads();

        #pragma unroll
        for (int ms = 0; ms < 4; ++ms) {
            // scores with current kfp
            f32x4 sa[2];
            sa[0] = (f32x4){0.f, 0.f, 0.f, 0.f};
            sa[1] = (f32x4){0.f, 0.f, 0.f, 0.f};
            #pragma unroll
            for (int cc = 0; cc < 4; ++cc) {
                sa[0] = __builtin_amdgcn_mfma_f32_16x16x32_f16(kfp[cc], qf[0][cc], sa[0], 0, 0, 0);
                sa[1] = __builtin_amdgcn_mfma_f32_16x16x32_f16(kfp[cc], qf[1][cc], sa[1], 0, 0, 0);
            }
            // prefetch next ms-group (wraps to m=0 at the very end; always in-bounds)
            {
                const int nm0 = (ms == 3) ? ((m0 + 64) & (NP - 1)) : m0;
                const int nms = (ms + 1) & 3;
                #pragma unroll
                for (int cc = 0; cc < 4; ++cc)
                    kfp[cc] = *(const f16x8*)&K[(size_t)(nm0 + nms * 16 + lr) * EMB + cc * 32 + quad * 8];
            }
            // exp2 -> f16 pack (x16 A-frag: k = quad*4 + j)
            f16x4 ppk[2];
            #pragma unroll
            for (int nt = 0; nt < 2; ++nt) {
                const float e0 = __builtin_amdgcn_exp2f(sa[nt][0]);
                const float e1 = __builtin_amdgcn_exp2f(sa[nt][1]);
                const float e2 = __builtin_amdgcn_exp2f(sa[nt][2]);
                const float e3 = __builtin_amdgcn_exp2f(sa[nt][3]);
                rs[nt] += (e0 + e1) + (e2 + e3);
                f16x4 pp;
                pp[0] = (f16)e0; pp[1] = (f16)e1; pp[2] = (f16)e2; pp[3] = (f16)e3;
                ppk[nt] = pp;
            }
            // PV: O[q][d] += P . V
            #pragma unroll
            for (int dt = 0; dt < 8; ++dt) {
                const f16x4 vf = *(const f16x4*)&Vl[dt * 16 + lr][ms * 16 + quad * 4];
                O[0][dt] = __builtin_amdgcn_mfma_f32_16x16x16f16(ppk[0], vf, O[0][dt], 0, 0, 0);
                O[1][dt] = __builtin_amdgcn_mfma_f32_16x16x16f16(ppk[1], vf, O[1][dt], 0, 0, 0);
            }
        }
    }

    #pragma unroll
    for (int nt = 0; nt < 2; ++nt) {
        rs[nt] += __shfl_xor(rs[nt], 16);
        rs[nt] += __shfl_xor(rs[nt], 32);
    }
    #pragma unroll
    for (int nt = 0; nt < 2; ++nt) {
        float iv[4];
        #pragma unroll
        for (int r = 0; r < 4; ++r)
            iv[r] = 1.0f / __shfl(rs[nt], quad * 4 + r, 64);
        #pragma unroll
        for (int dt = 0; dt < 8; ++dt)
            #pragma unroll
            for (int r = 0; r < 4; ++r) {
                const int n = qbase + nt * 16 + quad * 4 + r;
                combT[((size_t)b * NP + n) * OUTC + dir * EMB + dt * 16 + lr] =
                    (f16)(O[nt][dt][r] * iv[r]);
            }
    }
}

// =======================================================================
// proj_out: f16 GEMM + BN + ReLU, fp32 output.
// =======================================================================
__global__ __launch_bounds__(256) void proj_out_kernel(
    const f16* __restrict__ combT, const f16* __restrict__ Wp,
    const float* __restrict__ G, const float* __restrict__ Be,
    const float* __restrict__ Mu, const float* __restrict__ Va,
    float* __restrict__ out)
{
    const int m0 = blockIdx.x * 128;
    const int o0 = blockIdx.y * 128;
    const int b  = blockIdx.z;
    const int tid = threadIdx.x;
    const int w = tid >> 6, lane = tid & 63, quad = lane >> 4, lr = lane & 15;

    __shared__ __align__(16) f16 smem[128 * 72 * 2];
    f16* Al = smem;
    f16* Bl = smem + 128 * 72;

    f32x4 acc[2][8];
    #pragma unroll
    for (int mi = 0; mi < 2; ++mi)
        #pragma unroll
        for (int ni = 0; ni < 8; ++ni) acc[mi][ni] = (f32x4){0.f, 0.f, 0.f, 0.f};

    for (int kt = 0; kt < 4; ++kt) {
        const int kc0 = kt * 64;
        __syncthreads();
        #pragma unroll
        for (int i = 0; i < 4; ++i) {
            const int s2 = i * 256 + tid;
            const int n = s2 >> 3, cg = s2 & 7;
            *(f16x8*)&Al[n * 72 + cg * 8] =
                *(const f16x8*)&combT[((size_t)b * NP + m0 + n) * OUTC + kc0 + cg * 8];
        }
        #pragma unroll
        for (int i = 0; i < 4; ++i) {
            const int s2 = i * 256 + tid;
            const int d = s2 >> 3, cg = s2 & 7;
            *(f16x8*)&Bl[d * 72 + cg * 8] =
                *(const f16x8*)&Wp[(size_t)(o0 + d) * OUTC + kc0 + cg * 8];
        }
        __syncthreads();
        #pragma unroll
        for (int ks = 0; ks < 2; ++ks) {
            f16x8 af[2], bfr[8];
            #pragma unroll
            for (int mi = 0; mi < 2; ++mi)
                af[mi] = *(const f16x8*)&Al[(w * 32 + mi * 16 + lr) * 72 + ks * 32 + quad * 8];
            #pragma unroll
            for (int ni = 0; ni < 8; ++ni)
                bfr[ni] = *(const f16x8*)&Bl[(ni * 16 + lr) * 72 + ks * 32 + quad * 8];
            #pragma unroll
            for (int mi = 0; mi < 2; ++mi)
                #pragma unroll
                for (int ni = 0; ni < 8; ++ni)
                    acc[mi][ni] = __builtin_amdgcn_mfma_f32_16x16x32_f16(
                        af[mi], bfr[ni], acc[mi][ni], 0, 0, 0);
        }
    }

    __syncthreads();
    f16* T = smem;   // [128 o][136]
    #pragma unroll
    for (int ni = 0; ni < 8; ++ni) {
        const int o = o0 + ni * 16 + lr;
        const float iv = G[o] * rsqrtf(Va[o] + BN_EPS);
        const float sh = Be[o] - Mu[o] * iv;
        #pragma unroll
        for (int mi = 0; mi < 2; ++mi)
            #pragma unroll
            for (int r = 0; r < 4; ++r)
                T[(ni * 16 + lr) * 136 + w * 32 + mi * 16 + quad * 4 + r] =
                    (f16)fmaxf(acc[mi][ni][r] * iv + sh, 0.f);
    }
    __syncthreads();
    for (int s2 = tid; s2 < 2048; s2 += 256) {
        const int o = s2 >> 4, n8 = (s2 & 15) * 8;
        const f16x8 v = *(const f16x8*)&T[o * 136 + n8];
        const size_t off = ((size_t)b * OUTC + o0 + o) * NP + m0 + n8;
        #pragma unroll
        for (int k = 0; k < 8; ++k) out[off + k] = (float)v[k];
    }
}

extern "C" void kernel_launch(void* const* d_in, const int* in_sizes, int n_in,
                              void* d_out, int out_size, void* d_ws, size_t ws_size,
                              hipStream_t stream) {
    const float* f_rgb   = (const float*)d_in[0];
    const float* f_pl    = (const float*)d_in[1];
    const float* w_q_rgb = (const float*)d_in[2];  const float* b_q_rgb = (const float*)d_in[3];
    const float* w_k_pl  = (const float*)d_in[4];  const float* b_k_pl  = (const float*)d_in[5];
    const float* w_v_pl  = (const float*)d_in[6];  const float* b_v_pl  = (const float*)d_in[7];
    const float* w_q_pl  = (const float*)d_in[8];  const float* b_q_pl  = (const float*)d_in[9];
    const float* w_k_rgb = (const float*)d_in[10]; const float* b_k_rgb = (const float*)d_in[11];
    const float* w_v_rgb = (const float*)d_in[12]; const float* b_v_rgb = (const float*)d_in[13];
    const float* w_proj  = (const float*)d_in[14];
    const float* bn_g    = (const float*)d_in[15]; const float* bn_b = (const float*)d_in[16];
    const float* bn_m    = (const float*)d_in[17]; const float* bn_v = (const float*)d_in[18];

    // ws layout (halves): Qt | Kt | Vn | XT(=combT, one stream at a time) | Wf | Bf
    f16* Qt = (f16*)d_ws;
    f16* Kt = Qt + TSZ;
    f16* Vn = Kt + TSZ;
    f16* XT = Vn + TSZ;                         // 8,388,608 halves (reused as combT)
    f16* Wf = XT + (size_t)NB * NP * CINC;      // 262,144 halves
    f16* Bf = Wf + 262144;                      // 768 halves
    f16* combT = XT;

    prep_w_kernel<<<1027, 256, 0, stream>>>(
        w_q_rgb, w_k_rgb, w_v_rgb, w_q_pl, w_k_pl, w_v_pl, w_proj,
        b_q_rgb, b_k_rgb, b_v_rgb, b_q_pl, b_k_pl, b_v_pl, Wf, Bf);

    // stream 0 = rgb: Q->dir0, K->dir1, V->dir1
    prep_x_kernel<<<dim3(64, 4, 8), 256, 0, stream>>>(f_rgb, XT);
    proj6_kernel<<<dim3(32, 3, 8), 256, 0, stream>>>(XT, Wf, Bf, 0, Qt, Kt, Vn);
    // stream 1 = pl: Q->dir1, K->dir0, V->dir0
    prep_x_kernel<<<dim3(64, 4, 8), 256, 0, stream>>>(f_pl, XT);
    proj6_kernel<<<dim3(32, 3, 8), 256, 0, stream>>>(XT, Wf, Bf, 3, Qt, Kt, Vn);

    attn_kernel<<<512, 256, 0, stream>>>(Qt, Kt, Vn, combT);

    proj_out_kernel<<<dim3(32, 2, 8), 256, 0, stream>>>(
        combT, Wf + 196608, bn_g, bn_b, bn_m, bn_v, (float*)d_out);
}

// Round 7
// 354.370 us; speedup vs baseline: 1.4322x; 1.4322x over previous
//
#include <hip/hip_runtime.h>
#include <hip/hip_bf16.h>
#include <hip/hip_fp16.h>

typedef _Float16 f16;
typedef _Float16 f16x8 __attribute__((ext_vector_type(8)));
typedef _Float16 f16x4 __attribute__((ext_vector_type(4)));
typedef float f32x4 __attribute__((ext_vector_type(4)));

#define NP   4096   // H*W
#define NB   8      // batch
#define CINC 256    // input channels
#define EMB  128
#define OUTC 256
#define BN_EPS 1e-5f

#define DSZ  ((size_t)NB * NP * EMB)      // 4194304 halves, per-dir tensor
#define TSZ  (2 * DSZ)                    // 8388608 halves

// =======================================================================
// Kernel 1: ALL 6 input projections in one launch. grid (32, 6, 8).
//   p = blockIdx.y: 0..2 = rgb stream (q_rgb,k_rgb,v_rgb), 3..5 = pl stream.
//   j = p%3: 0 -> Q[s] ([b][n][128]) ; 1 -> K[1-s] ; 2 -> V[1-s] ([b][d][4096])
// fp32 inputs staged+converted to f16 in-kernel (per-launch-overhead >> this).
// =======================================================================
__global__ __launch_bounds__(256) void proj_all_kernel(
    const float* __restrict__ Xrgb, const float* __restrict__ Xpl,
    const float* __restrict__ w0, const float* __restrict__ b0,
    const float* __restrict__ w1, const float* __restrict__ b1,
    const float* __restrict__ w2, const float* __restrict__ b2,
    const float* __restrict__ w3, const float* __restrict__ b3,
    const float* __restrict__ w4, const float* __restrict__ b4,
    const float* __restrict__ w5, const float* __restrict__ b5,
    f16* __restrict__ Qt, f16* __restrict__ Kt, f16* __restrict__ Vn)
{
    const int m0 = blockIdx.x * 128;
    const int p  = blockIdx.y;
    const int b  = blockIdx.z;
    const int s  = (p >= 3) ? 1 : 0;
    const int j  = p - s * 3;
    const int tid = threadIdx.x;
    const int w = tid >> 6, lane = tid & 63, quad = lane >> 4, lr = lane & 15;

    const float* X  = s ? Xpl : Xrgb;
    const float* W  = p == 0 ? w0 : p == 1 ? w1 : p == 2 ? w2
                    : p == 3 ? w3 : p == 4 ? w4 : w5;
    const float* Bi = p == 0 ? b0 : p == 1 ? b1 : p == 2 ? b2
                    : p == 3 ? b3 : p == 4 ? b4 : b5;

    __shared__ __align__(16) f16 smem[128 * 72 * 2];   // 36864 B
    f16* Al = smem;             // [128 n][72]
    f16* Bl = smem + 128 * 72;  // [128 d][72]

    f32x4 acc[2][8];
    #pragma unroll
    for (int mi = 0; mi < 2; ++mi)
        #pragma unroll
        for (int ni = 0; ni < 8; ++ni) acc[mi][ni] = (f32x4){0.f, 0.f, 0.f, 0.f};

    for (int kt = 0; kt < 4; ++kt) {
        const int kc0 = kt * 64;
        __syncthreads();
        // A: X[c][n] -> Al[n][c] (transpose + convert); lanes coalesced over n
        for (int s2 = tid; s2 < 1024; s2 += 256) {
            const int n = s2 & 127, cg = s2 >> 7;
            f16 tmp[8];
            #pragma unroll
            for (int jj = 0; jj < 8; ++jj)
                tmp[jj] = (f16)X[((size_t)b * CINC + kc0 + cg * 8 + jj) * NP + m0 + n];
            *(f16x8*)&Al[n * 72 + cg * 8] = *(const f16x8*)tmp;
        }
        // B: W[d][c] contiguous fp32 -> convert
        for (int s2 = tid; s2 < 1024; s2 += 256) {
            const int d = s2 >> 3, cg = s2 & 7;
            f16 tmp[8];
            #pragma unroll
            for (int jj = 0; jj < 8; ++jj)
                tmp[jj] = (f16)W[(size_t)d * CINC + kc0 + cg * 8 + jj];
            *(f16x8*)&Bl[d * 72 + cg * 8] = *(const f16x8*)tmp;
        }
        __syncthreads();
        #pragma unroll
        for (int ks = 0; ks < 2; ++ks) {
            f16x8 af[2], bfr[8];
            #pragma unroll
            for (int mi = 0; mi < 2; ++mi)
                af[mi] = *(const f16x8*)&Al[(w * 32 + mi * 16 + lr) * 72 + ks * 32 + quad * 8];
            #pragma unroll
            for (int ni = 0; ni < 8; ++ni)
                bfr[ni] = *(const f16x8*)&Bl[(ni * 16 + lr) * 72 + ks * 32 + quad * 8];
            #pragma unroll
            for (int mi = 0; mi < 2; ++mi)
                #pragma unroll
                for (int ni = 0; ni < 8; ++ni)
                    acc[mi][ni] = __builtin_amdgcn_mfma_f32_16x16x32_f16(
                        af[mi], bfr[ni], acc[mi][ni], 0, 0, 0);
        }
    }

    float bias[8];
    #pragma unroll
    for (int ni = 0; ni < 8; ++ni) bias[ni] = Bi[ni * 16 + lr];

    if (j < 2) {
        f16* out = (j == 0) ? (Qt + (size_t)s * DSZ) : (Kt + (size_t)(1 - s) * DSZ);
        #pragma unroll
        for (int mi = 0; mi < 2; ++mi)
            #pragma unroll
            for (int ni = 0; ni < 8; ++ni)
                #pragma unroll
                for (int r = 0; r < 4; ++r) {
                    const int n = m0 + w * 32 + mi * 16 + quad * 4 + r;
                    out[((size_t)b * NP + n) * EMB + ni * 16 + lr] =
                        (f16)(acc[mi][ni][r] + bias[ni]);
                }
    } else {
        f16* outV = Vn + (size_t)(1 - s) * DSZ;
        __syncthreads();
        f16* T = smem;                        // [128 d][136]
        #pragma unroll
        for (int mi = 0; mi < 2; ++mi)
            #pragma unroll
            for (int ni = 0; ni < 8; ++ni)
                #pragma unroll
                for (int r = 0; r < 4; ++r)
                    T[(ni * 16 + lr) * 136 + w * 32 + mi * 16 + quad * 4 + r] =
                        (f16)(acc[mi][ni][r] + bias[ni]);
        __syncthreads();
        for (int s2 = tid; s2 < 2048; s2 += 256) {
            const int d = s2 >> 4, n8 = (s2 & 15) * 8;
            *(f16x8*)&outV[((size_t)b * EMB + d) * NP + m0 + n8] =
                *(const f16x8*)&T[d * 136 + n8];
        }
    }
}

// =======================================================================
// Kernel 2: flash attention (R5 structure: Kl+Vl in LDS). 4 waves/block,
// 32 q/wave. 1-D XCD-swizzled grid: bid&15 -> (dir,b), bid>>4 -> n-block,
// so the 32 blocks sharing one (dir,b)'s K/V land on the same L2s.
// S^T via x32 (A=K, B=Q) -> exp2 -> P lands in x16 A-layout -> PV, no
// LDS round-trip for P.
// =======================================================================
__global__ __launch_bounds__(256, 2) void attn_kernel(
    const f16* __restrict__ Qt, const f16* __restrict__ Kt,
    const f16* __restrict__ Vn, f16* __restrict__ combT)
{
    const int bid = blockIdx.x;
    const int g = bid & 15, dir = g >> 3, b = g & 7;
    const int n0 = (bid >> 4) * 128;
    const int tid = threadIdx.x;
    const int w = tid >> 6, lane = tid & 63, quad = lane >> 4, lr = lane & 15;

    const f16* Q = Qt + ((size_t)dir * NB + b) * NP * EMB;
    const f16* K = Kt + ((size_t)dir * NB + b) * NP * EMB;
    const f16* V = Vn + ((size_t)dir * NB + b) * (size_t)EMB * NP;

    __shared__ __align__(16) f16 Kl[64][136];   // [m][d]
    __shared__ __align__(16) f16 Vl[128][72];   // [d][m]

    const int qbase = n0 + w * 32;

    // Q B-frags: col n = lr, k = cc*32 + quad*8 + j. scale*log2(e) folded.
    f16x8 qf[2][4];
    #pragma unroll
    for (int nt = 0; nt < 2; ++nt)
        #pragma unroll
        for (int cc = 0; cc < 4; ++cc) {
            f16x8 q = *(const f16x8*)&Q[(size_t)(qbase + nt * 16 + lr) * EMB + cc * 32 + quad * 8];
            #pragma unroll
            for (int k = 0; k < 8; ++k)
                q[k] = q[k] * (f16)0.12752749f;   // 128^-0.5 * log2(e)
            qf[nt][cc] = q;
        }

    f32x4 O[2][8];
    #pragma unroll
    for (int nt = 0; nt < 2; ++nt)
        #pragma unroll
        for (int dt = 0; dt < 8; ++dt) O[nt][dt] = (f32x4){0.f, 0.f, 0.f, 0.f};
    float rs[2] = {0.f, 0.f};

    for (int m0 = 0; m0 < NP; m0 += 64) {
        __syncthreads();
        #pragma unroll
        for (int i = 0; i < 4; ++i) {            // K tile: 64 m x 128 d
            const int s2 = i * 256 + tid;
            const int mm = s2 >> 4, dc = s2 & 15;
            *(f16x8*)&Kl[mm][dc * 8] = *(const f16x8*)&K[(size_t)(m0 + mm) * EMB + dc * 8];
        }
        #pragma unroll
        for (int i = 0; i < 4; ++i) {            // V tile: 128 d x 64 m
            const int s2 = i * 256 + tid;
            const int d = s2 >> 3, mc = s2 & 7;
            *(f16x8*)&Vl[d][mc * 8] = *(const f16x8*)&V[(size_t)d * NP + m0 + mc * 8];
        }
        __syncthreads();

        #pragma unroll
        for (int ms = 0; ms < 4; ++ms) {
            // K A-frags for this 16-key group (shared across both nt)
            f16x8 kf[4];
            #pragma unroll
            for (int cc = 0; cc < 4; ++cc)
                kf[cc] = *(const f16x8*)&Kl[ms * 16 + lr][cc * 32 + quad * 8];

            // S^T[key=quad*4+r][query=nt*16+lr] -> exp2 -> x16 A-frag
            f16x4 ppk[2];
            #pragma unroll
            for (int nt = 0; nt < 2; ++nt) {
                f32x4 sa = (f32x4){0.f, 0.f, 0.f, 0.f};
                #pragma unroll
                for (int cc = 0; cc < 4; ++cc)
                    sa = __builtin_amdgcn_mfma_f32_16x16x32_f16(kf[cc], qf[nt][cc], sa, 0, 0, 0);
                const float e0 = __builtin_amdgcn_exp2f(sa[0]);
                const float e1 = __builtin_amdgcn_exp2f(sa[1]);
                const float e2 = __builtin_amdgcn_exp2f(sa[2]);
                const float e3 = __builtin_amdgcn_exp2f(sa[3]);
                rs[nt] += (e0 + e1) + (e2 + e3);
                f16x4 pp;
                pp[0] = (f16)e0; pp[1] = (f16)e1; pp[2] = (f16)e2; pp[3] = (f16)e3;
                ppk[nt] = pp;
            }

            // PV: O[q][d] += P . V  (16x16x16, k = quad*4 + j)
            #pragma unroll
            for (int dt = 0; dt < 8; ++dt) {
                const f16x4 vf = *(const f16x4*)&Vl[dt * 16 + lr][ms * 16 + quad * 4];
                O[0][dt] = __builtin_amdgcn_mfma_f32_16x16x16f16(ppk[0], vf, O[0][dt], 0, 0, 0);
                O[1][dt] = __builtin_amdgcn_mfma_f32_16x16x16f16(ppk[1], vf, O[1][dt], 0, 0, 0);
            }
        }
    }

    #pragma unroll
    for (int nt = 0; nt < 2; ++nt) {
        rs[nt] += __shfl_xor(rs[nt], 16);
        rs[nt] += __shfl_xor(rs[nt], 32);
    }
    #pragma unroll
    for (int nt = 0; nt < 2; ++nt) {
        float iv[4];
        #pragma unroll
        for (int r = 0; r < 4; ++r)
            iv[r] = 1.0f / __shfl(rs[nt], quad * 4 + r, 64);
        #pragma unroll
        for (int dt = 0; dt < 8; ++dt)
            #pragma unroll
            for (int r = 0; r < 4; ++r) {
                const int n = qbase + nt * 16 + quad * 4 + r;
                combT[((size_t)b * NP + n) * OUTC + dir * EMB + dt * 16 + lr] =
                    (f16)(O[nt][dt][r] * iv[r]);
            }
    }
}

// =======================================================================
// Kernel 3: output projection GEMM (MFMA) + BN + ReLU, fp32 out.
// W staged+converted fp32->f16 in-kernel.
// =======================================================================
__global__ __launch_bounds__(256) void proj_out_kernel(
    const f16* __restrict__ combT, const float* __restrict__ Wp,
    const float* __restrict__ G, const float* __restrict__ Be,
    const float* __restrict__ Mu, const float* __restrict__ Va,
    float* __restrict__ out)
{
    const int m0 = blockIdx.x * 128;
    const int o0 = blockIdx.y * 128;
    const int b  = blockIdx.z;
    const int tid = threadIdx.x;
    const int w = tid >> 6, lane = tid & 63, quad = lane >> 4, lr = lane & 15;

    __shared__ __align__(16) f16 smem[128 * 72 * 2];
    f16* Al = smem;
    f16* Bl = smem + 128 * 72;

    f32x4 acc[2][8];
    #pragma unroll
    for (int mi = 0; mi < 2; ++mi)
        #pragma unroll
        for (int ni = 0; ni < 8; ++ni) acc[mi][ni] = (f32x4){0.f, 0.f, 0.f, 0.f};

    for (int kt = 0; kt < 4; ++kt) {
        const int kc0 = kt * 64;
        __syncthreads();
        #pragma unroll
        for (int i = 0; i < 4; ++i) {     // A tile: f16 straight copy
            const int s2 = i * 256 + tid;
            const int n = s2 >> 3, cg = s2 & 7;
            *(f16x8*)&Al[n * 72 + cg * 8] =
                *(const f16x8*)&combT[((size_t)b * NP + m0 + n) * OUTC + kc0 + cg * 8];
        }
        for (int s2 = tid; s2 < 1024; s2 += 256) {  // B tile: fp32 -> f16
            const int d = s2 >> 3, cg = s2 & 7;
            f16 tmp[8];
            #pragma unroll
            for (int jj = 0; jj < 8; ++jj)
                tmp[jj] = (f16)Wp[(size_t)(o0 + d) * OUTC + kc0 + cg * 8 + jj];
            *(f16x8*)&Bl[d * 72 + cg * 8] = *(const f16x8*)tmp;
        }
        __syncthreads();
        #pragma unroll
        for (int ks = 0; ks < 2; ++ks) {
            f16x8 af[2], bfr[8];
            #pragma unroll
            for (int mi = 0; mi < 2; ++mi)
                af[mi] = *(const f16x8*)&Al[(w * 32 + mi * 16 + lr) * 72 + ks * 32 + quad * 8];
            #pragma unroll
            for (int ni = 0; ni < 8; ++ni)
                bfr[ni] = *(const f16x8*)&Bl[(ni * 16 + lr) * 72 + ks * 32 + quad * 8];
            #pragma unroll
            for (int mi = 0; mi < 2; ++mi)
                #pragma unroll
                for (int ni = 0; ni < 8; ++ni)
                    acc[mi][ni] = __builtin_amdgcn_mfma_f32_16x16x32_f16(
                        af[mi], bfr[ni], acc[mi][ni], 0, 0, 0);
        }
    }

    __syncthreads();
    f16* T = smem;   // [128 o][136]
    #pragma unroll
    for (int ni = 0; ni < 8; ++ni) {
        const int o = o0 + ni * 16 + lr;
        const float iv = G[o] * rsqrtf(Va[o] + BN_EPS);
        const float sh = Be[o] - Mu[o] * iv;
        #pragma unroll
        for (int mi = 0; mi < 2; ++mi)
            #pragma unroll
            for (int r = 0; r < 4; ++r)
                T[(ni * 16 + lr) * 136 + w * 32 + mi * 16 + quad * 4 + r] =
                    (f16)fmaxf(acc[mi][ni][r] * iv + sh, 0.f);
    }
    __syncthreads();
    for (int s2 = tid; s2 < 2048; s2 += 256) {
        const int o = s2 >> 4, n8 = (s2 & 15) * 8;
        const f16x8 v = *(const f16x8*)&T[o * 136 + n8];
        const size_t off = ((size_t)b * OUTC + o0 + o) * NP + m0 + n8;
        #pragma unroll
        for (int k = 0; k < 8; ++k) out[off + k] = (float)v[k];
    }
}

extern "C" void kernel_launch(void* const* d_in, const int* in_sizes, int n_in,
                              void* d_out, int out_size, void* d_ws, size_t ws_size,
                              hipStream_t stream) {
    const float* f_rgb   = (const float*)d_in[0];
    const float* f_pl    = (const float*)d_in[1];
    const float* w_q_rgb = (const float*)d_in[2];  const float* b_q_rgb = (const float*)d_in[3];
    const float* w_k_pl  = (const float*)d_in[4];  const float* b_k_pl  = (const float*)d_in[5];
    const float* w_v_pl  = (const float*)d_in[6];  const float* b_v_pl  = (const float*)d_in[7];
    const float* w_q_pl  = (const float*)d_in[8];  const float* b_q_pl  = (const float*)d_in[9];
    const float* w_k_rgb = (const float*)d_in[10]; const float* b_k_rgb = (const float*)d_in[11];
    const float* w_v_rgb = (const float*)d_in[12]; const float* b_v_rgb = (const float*)d_in[13];
    const float* w_proj  = (const float*)d_in[14];
    const float* bn_g    = (const float*)d_in[15]; const float* bn_b = (const float*)d_in[16];
    const float* bn_m    = (const float*)d_in[17]; const float* bn_v = (const float*)d_in[18];

    // ws (halves): Qt | Kt | Vn | combT  = 4 * TSZ = 67.1 MB
    f16* Qt    = (f16*)d_ws;
    f16* Kt    = Qt + TSZ;
    f16* Vn    = Kt + TSZ;
    f16* combT = Vn + TSZ;

    // p: 0=q_rgb 1=k_rgb 2=v_rgb (stream rgb) ; 3=q_pl 4=k_pl 5=v_pl (stream pl)
    // j=0 -> Q[s]; j=1 -> K[1-s]; j=2 -> V[1-s]
    proj_all_kernel<<<dim3(32, 6, 8), 256, 0, stream>>>(
        f_rgb, f_pl,
        w_q_rgb, b_q_rgb, w_k_rgb, b_k_rgb, w_v_rgb, b_v_rgb,
        w_q_pl,  b_q_pl,  w_k_pl,  b_k_pl,  w_v_pl,  b_v_pl,
        Qt, Kt, Vn);

    attn_kernel<<<512, 256, 0, stream>>>(Qt, Kt, Vn, combT);

    proj_out_kernel<<<dim3(32, 2, 8), 256, 0, stream>>>(
        combT, w_proj, bn_g, bn_b, bn_m, bn_v, (float*)d_out);
}